// Round 2
// baseline (318.170 us; speedup 1.0000x reference)
//
#include <hip/hip_runtime.h>
#include <hip/hip_bf16.h>

typedef __attribute__((ext_vector_type(8))) short short8;
typedef __attribute__((ext_vector_type(4))) short short4b;
typedef __attribute__((ext_vector_type(4))) float f32x4;

#define S_LEN 2048
#define DIM   64
#define BR    64
#define BC    64
#define NKT   (S_LEN / BC)   // 32

// pitches (padded to avoid LDS bank conflicts, keep 16B alignment where b128 reads occur)
#define KP  72   // K/Vt row pitch in shorts (= 36 dwords = 144B)
#define BP  33   // bits row pitch in u64   (= 66 dwords = 264B)
#define AP  68   // attn-bounce row pitch in floats (= 272B, 16B aligned)

__device__ __forceinline__ short f2bf(float f) {
    __hip_bfloat16 h = __float2bfloat16(f);
    return __builtin_bit_cast(short, h);
}

__global__ __launch_bounds__(256, 3)
void sdpa_kernel(const float* __restrict__ q, const float* __restrict__ k,
                 const float* __restrict__ v, const int* __restrict__ mask,
                 float* __restrict__ out, float* __restrict__ attn)
{
    __shared__ __align__(16) short Klds[BR * KP];                  // 9.2 KB
    __shared__ __align__(16) short Vtlds[DIM * KP];                // 9.2 KB
    __shared__ __align__(16) unsigned long long Bits[BR * BP];     // 16.9 KB
    __shared__ __align__(16) float Albs[BR * AP];                  // 17.4 KB

    const int t  = threadIdx.x;
    const int l  = t & 63;
    const int wv = t >> 6;        // wave 0..3
    const int lg = l >> 4;        // lane group 0..3
    const int ll = l & 15;

    const int wg = blockIdx.x;
    const int b  = wg >> 5;                // 32 row-blocks per batch
    const int i0 = (wg & 31) * BR;

    const float LOG2E_T = 0.18033688011112042f;   // log2(e) / 8

    // ---- Q fragments: A[row=i][k=d], lane: i = i0+16*wv+ll, d = s*32 + lg*8 + m ----
    short8 qf[2];
    {
        const float* qrow = q + ((size_t)(b * S_LEN + i0 + 16 * wv + ll) * DIM);
        #pragma unroll
        for (int s = 0; s < 2; ++s) {
            const float* p = qrow + s * 32 + lg * 8;
            float4 a = *(const float4*)p;
            float4 c = *(const float4*)(p + 4);
            short8 f;
            f[0]=f2bf(a.x); f[1]=f2bf(a.y); f[2]=f2bf(a.z); f[3]=f2bf(a.w);
            f[4]=f2bf(c.x); f[5]=f2bf(c.y); f[6]=f2bf(c.z); f[7]=f2bf(c.w);
            qf[s] = f;
        }
    }

    float rs[4] = {0.f, 0.f, 0.f, 0.f};

    // ================= Phase 1: rowsums + bit-pack mask into LDS =================
    for (int kt = 0; kt < NKT; ++kt) {
        const int j0 = kt * BC;

        // stage K tile -> Klds (bf16 row-major [j][d], pitch KP)
        #pragma unroll
        for (int p = 0; p < 4; ++p) {
            int row = (t >> 4) + p * 16;
            int dd  = (t & 15) * 4;
            float4 kv4 = *(const float4*)(k + ((size_t)(b * S_LEN + j0 + row) * DIM + dd));
            short4b s4;
            s4[0]=f2bf(kv4.x); s4[1]=f2bf(kv4.y); s4[2]=f2bf(kv4.z); s4[3]=f2bf(kv4.w);
            *(short4b*)&Klds[row * KP + dd] = s4;
        }

        // mask rows -> ballot u64 -> Bits (wave handles its own 16 q-rows)
        {
            const int* mrow = mask + (size_t)(b * S_LEN + i0 + 16 * wv) * S_LEN + j0 + l;
            int mv[16];
            #pragma unroll
            for (int r = 0; r < 16; ++r)
                mv[r] = __builtin_nontemporal_load(mrow + (size_t)r * S_LEN);
            unsigned long long myword = 0ull;
            #pragma unroll
            for (int r = 0; r < 16; ++r) {
                unsigned long long bal = __ballot(mv[r] != 0);
                if (ll == r) myword = bal;
            }
            if (l < 16) Bits[(16 * wv + l) * BP + kt] = myword;
        }
        __syncthreads();

        unsigned long long wbits[4];
        #pragma unroll
        for (int r = 0; r < 4; ++r)
            wbits[r] = Bits[(16 * wv + lg * 4 + r) * BP + kt];

        #pragma unroll
        for (int jt = 0; jt < 4; ++jt) {
            short8 b0 = *(short8*)&Klds[(jt * 16 + ll) * KP + lg * 8];
            short8 b1 = *(short8*)&Klds[(jt * 16 + ll) * KP + 32 + lg * 8];
            f32x4 c = {0.f, 0.f, 0.f, 0.f};
            c = __builtin_amdgcn_mfma_f32_16x16x32_bf16(qf[0], b0, c, 0, 0, 0);
            c = __builtin_amdgcn_mfma_f32_16x16x32_bf16(qf[1], b1, c, 0, 0, 0);
            #pragma unroll
            for (int r = 0; r < 4; ++r) {
                unsigned int bit = (unsigned int)(wbits[r] >> (jt * 16 + ll)) & 1u;
                float pexp = bit ? 0.f : __builtin_amdgcn_exp2f(c[r] * LOG2E_T);
                rs[r] += pexp;
            }
        }
        __syncthreads();
    }

    // reduce rowsums across the 16 column-lanes (lane bits 0..3), invert
    float inv[4];
    #pragma unroll
    for (int r = 0; r < 4; ++r) {
        float s = rs[r];
        s += __shfl_xor(s, 1);
        s += __shfl_xor(s, 2);
        s += __shfl_xor(s, 4);
        s += __shfl_xor(s, 8);
        inv[r] = 1.0f / s;
    }

    // ================= Phase 2: normalized attn write + PV =================
    f32x4 oacc[4];
    #pragma unroll
    for (int dt = 0; dt < 4; ++dt) oacc[dt] = (f32x4){0.f, 0.f, 0.f, 0.f};

    for (int kt = 0; kt < NKT; ++kt) {
        const int j0 = kt * BC;

        // stage K tile
        #pragma unroll
        for (int p = 0; p < 4; ++p) {
            int row = (t >> 4) + p * 16;
            int dd  = (t & 15) * 4;
            float4 kv4 = *(const float4*)(k + ((size_t)(b * S_LEN + j0 + row) * DIM + dd));
            short4b s4;
            s4[0]=f2bf(kv4.x); s4[1]=f2bf(kv4.y); s4[2]=f2bf(kv4.z); s4[3]=f2bf(kv4.w);
            *(short4b*)&Klds[row * KP + dd] = s4;
        }
        // stage V tile transposed -> Vtlds[d][j] (bf16, pitch KP)
        #pragma unroll
        for (int it = 0; it < 8; ++it) {
            int jp = (t >> 4) + (it & 1) * 16;       // j-pair 0..31
            int dd = (t & 15) + (it >> 1) * 16;      // d 0..63
            const float* vp = v + ((size_t)(b * S_LEN + j0 + jp * 2) * DIM + dd);
            float v0 = vp[0];
            float v1 = vp[DIM];
            unsigned int pk = (unsigned int)(unsigned short)f2bf(v0) |
                              ((unsigned int)(unsigned short)f2bf(v1) << 16);
            *(unsigned int*)&Vtlds[dd * KP + jp * 2] = pk;
        }
        __syncthreads();

        unsigned long long wbits[4];
        #pragma unroll
        for (int r = 0; r < 4; ++r)
            wbits[r] = Bits[(16 * wv + lg * 4 + r) * BP + kt];

        // scores -> normalized p -> bounce into Albs (per-wave-private rows)
        #pragma unroll
        for (int jt = 0; jt < 4; ++jt) {
            short8 b0 = *(short8*)&Klds[(jt * 16 + ll) * KP + lg * 8];
            short8 b1 = *(short8*)&Klds[(jt * 16 + ll) * KP + 32 + lg * 8];
            f32x4 c = {0.f, 0.f, 0.f, 0.f};
            c = __builtin_amdgcn_mfma_f32_16x16x32_bf16(qf[0], b0, c, 0, 0, 0);
            c = __builtin_amdgcn_mfma_f32_16x16x32_bf16(qf[1], b1, c, 0, 0, 0);
            #pragma unroll
            for (int r = 0; r < 4; ++r) {
                unsigned int bit = (unsigned int)(wbits[r] >> (jt * 16 + ll)) & 1u;
                float pexp = bit ? 0.f : __builtin_amdgcn_exp2f(c[r] * LOG2E_T);
                float pn = pexp * inv[r];
                Albs[(16 * wv + lg * 4 + r) * AP + jt * 16 + ll] = pn;
            }
        }

        // A-fragments for PV from the bounce tile (transpose comes free)
        short8 paf[2];
        #pragma unroll
        for (int s = 0; s < 2; ++s) {
            const float* ap = &Albs[(16 * wv + ll) * AP + s * 32 + lg * 8];
            float4 x = *(const float4*)ap;
            float4 y = *(const float4*)(ap + 4);
            short8 f;
            f[0]=f2bf(x.x); f[1]=f2bf(x.y); f[2]=f2bf(x.z); f[3]=f2bf(x.w);
            f[4]=f2bf(y.x); f[5]=f2bf(y.y); f[6]=f2bf(y.z); f[7]=f2bf(y.w);
            paf[s] = f;
        }

        // PV: out[i][d] += P[i][j] * V[j][d]
        #pragma unroll
        for (int dt = 0; dt < 4; ++dt) {
            short8 b0 = *(short8*)&Vtlds[(dt * 16 + ll) * KP + lg * 8];
            short8 b1 = *(short8*)&Vtlds[(dt * 16 + ll) * KP + 32 + lg * 8];
            oacc[dt] = __builtin_amdgcn_mfma_f32_16x16x32_bf16(paf[0], b0, oacc[dt], 0, 0, 0);
            oacc[dt] = __builtin_amdgcn_mfma_f32_16x16x32_bf16(paf[1], b1, oacc[dt], 0, 0, 0);
        }

        // coalesced attn tile store (nontemporal, 256B per row)
        {
            float* abase = attn + (size_t)b * S_LEN * S_LEN;
            #pragma unroll
            for (int ps = 0; ps < 4; ++ps) {
                int row = 16 * wv + lg + ps * 4;
                f32x4 val = *(f32x4*)&Albs[row * AP + ll * 4];
                float* dst = abase + (size_t)(i0 + row) * S_LEN + j0 + ll * 4;
                __builtin_nontemporal_store(val, (f32x4*)dst);
            }
        }
        __syncthreads();
    }

    // final out write: C layout row=(lg*4+r), col=dt*16+ll
    #pragma unroll
    for (int dt = 0; dt < 4; ++dt)
        #pragma unroll
        for (int r = 0; r < 4; ++r)
            out[(size_t)(b * S_LEN + i0 + 16 * wv + lg * 4 + r) * DIM + dt * 16 + ll] = oacc[dt][r];
}

extern "C" void kernel_launch(void* const* d_in, const int* in_sizes, int n_in,
                              void* d_out, int out_size, void* d_ws, size_t ws_size,
                              hipStream_t stream) {
    const float* q    = (const float*)d_in[0];
    const float* k    = (const float*)d_in[1];
    const float* v    = (const float*)d_in[2];
    const int*   mask = (const int*)d_in[3];
    float* out  = (float*)d_out;
    float* attn = out + (size_t)32 * S_LEN * DIM;
    sdpa_kernel<<<dim3(32 * (S_LEN / BR)), dim3(256), 0, stream>>>(q, k, v, mask, out, attn);
}